// Round 22
// baseline (352.003 us; speedup 1.0000x reference)
//
#include <hip/hip_runtime.h>
#include <math.h>

typedef __bf16 bf16;
typedef bf16  bf16x8 __attribute__((ext_vector_type(8)));
typedef bf16  bf16x4 __attribute__((ext_vector_type(4)));
typedef bf16  bf16x2 __attribute__((ext_vector_type(2)));
typedef float f32x4  __attribute__((ext_vector_type(4)));
typedef float f32x2  __attribute__((ext_vector_type(2)));

#define BSH2 8        // bucket = 256 nodes
#define PCH  4096     // edges per partition chunk (391 blocks)
#define CAP  4608     // LDS record capacity per bucket (mean 4096, 8 sigma margin)

// ---------------- helpers ----------------

__global__ void zero_i32(int* __restrict__ p, int n) {
    int i = blockIdx.x * blockDim.x + threadIdx.x;
    if (i < n) p[i] = 0;
}

// ---------------- bucket histogram of dst>>8 (sequential read, LDS hist) ----------------

__global__ __launch_bounds__(256) void bhist_k(const int* __restrict__ dst,
                                               int* __restrict__ bhist, int E) {
    __shared__ int lh[512];
    for (int b = threadIdx.x; b < 512; b += 256) lh[b] = 0;
    __syncthreads();
    int i = blockIdx.x * 256 + threadIdx.x;
    int stride = gridDim.x * 256;
    for (; i < E; i += stride) atomicAdd(&lh[dst[i] >> BSH2], 1);
    __syncthreads();
    for (int b = threadIdx.x; b < 512; b += 256)
        if (lh[b]) atomicAdd(&bhist[b], lh[b]);
}

// single wave: exclusive scan bhist[512] -> ebase[513]
__global__ __launch_bounds__(64) void bscan512(const int* __restrict__ bhist,
                                               int* __restrict__ ebase) {
    int lane = threadIdx.x;
    __shared__ int carry_s;
    if (lane == 0) carry_s = 0;
    __syncthreads();
    for (int base = 0; base < 512; base += 64) {
        int v = bhist[base + lane];
        int x = v;
        #pragma unroll
        for (int o = 1; o < 64; o <<= 1) {
            int t = __shfl_up(x, o, 64);
            if (lane >= o) x += t;
        }
        int carry = carry_s;
        ebase[base + lane] = carry + x - v;
        int total = __shfl(x, 63, 64);
        __syncthreads();
        if (lane == 0) carry_s = carry + total;
        __syncthreads();
    }
    if (lane == 0) ebase[512] = carry_s;
}

// ---------------- pass 1: partition edges by dst bucket, coalesced runs ----------------

__global__ __launch_bounds__(256) void partition_edges(
    const int* __restrict__ src, const int* __restrict__ dst,
    const int* __restrict__ ebase, int* __restrict__ bcur,
    uint2* __restrict__ ebuf, int E, int nbk)
{
    __shared__ int lhist[512];
    __shared__ int lbase[512];
    __shared__ int lcur[512];
    __shared__ int gbase[512];
    __shared__ int csum[8];
    __shared__ unsigned short stage[PCH];

    const int tid = threadIdx.x, lane = tid & 63, wv = tid >> 6;

    for (int base = blockIdx.x * PCH; base < E; base += gridDim.x * PCH) {
        const int cnt = min(PCH, E - base);

        for (int b = tid; b < 512; b += 256) lhist[b] = 0;
        __syncthreads();
        for (int i = tid; i < cnt; i += 256)
            atomicAdd(&lhist[dst[base + i] >> BSH2], 1);
        __syncthreads();
        for (int c = wv; c < 8; c += 4) {
            int idx = c * 64 + lane;
            int v = lhist[idx], x = v;
            #pragma unroll
            for (int o = 1; o < 64; o <<= 1) {
                int t = __shfl_up(x, o, 64);
                if (lane >= o) x += t;
            }
            lbase[idx] = x - v;
            if (lane == 63) csum[c] = x;
        }
        __syncthreads();
        if (tid == 0) {
            int acc = 0;
            #pragma unroll
            for (int c = 0; c < 8; c++) { int t = csum[c]; csum[c] = acc; acc += t; }
        }
        __syncthreads();
        for (int c = wv; c < 8; c += 4) {
            int idx = c * 64 + lane;
            lbase[idx] += csum[c];
            lcur[idx] = lbase[idx];
        }
        __syncthreads();
        for (int i = tid; i < cnt; i += 256) {
            int b = dst[base + i] >> BSH2;
            int p = atomicAdd(&lcur[b], 1);
            stage[p] = (unsigned short)i;
        }
        __syncthreads();
        for (int b = tid; b < nbk; b += 256) {
            int cb = lcur[b] - lbase[b];
            if (cb > 0) gbase[b] = ebase[b] + atomicAdd(&bcur[b], cb);
        }
        __syncthreads();
        for (int k = tid; k < cnt; k += 256) {
            int i = base + (int)stage[k];
            int s = src[i], d = dst[i];
            int b = d >> BSH2;
            ebuf[gbase[b] + (k - lbase[b])] = make_uint2((unsigned)s, (unsigned)d);
        }
        __syncthreads();
    }
}

// ---------------- pass 1.5: per-bucket deg count -> off[] and dinv[]; zeroes gcur ----------------

__global__ __launch_bounds__(256) void bucket_off_dinv(
    const uint2* __restrict__ ebuf, const int* __restrict__ ebase,
    int* __restrict__ off, float* __restrict__ dinv, int* __restrict__ gcur,
    int n, int nbk)
{
    __shared__ int ldeg[256];
    __shared__ int wsum[4];
    const int tid = threadIdx.x, lane = tid & 63, wv = tid >> 6;

    for (int b = blockIdx.x; b < nbk; b += gridDim.x) {
        const int n0 = b << BSH2;
        const int n1 = min(n0 + 256, n);
        const int e0 = ebase[b], e1 = ebase[b + 1];

        ldeg[tid] = 0;
        __syncthreads();
        for (int i = e0 + tid; i < e1; i += 256)
            atomicAdd(&ldeg[(int)ebuf[i].y - n0], 1);
        __syncthreads();

        int v = ldeg[tid];
        int x = v;
        #pragma unroll
        for (int o = 1; o < 64; o <<= 1) {
            int t = __shfl_up(x, o, 64);
            if (lane >= o) x += t;
        }
        if (lane == 63) wsum[wv] = x;
        __syncthreads();
        int wbase = 0;
        #pragma unroll
        for (int w = 0; w < 4; w++) if (w < wv) wbase += wsum[w];
        int pref = wbase + x - v;   // exclusive prefix

        if (n0 + tid < n1) {
            off[n0 + tid]  = e0 + pref;
            dinv[n0 + tid] = rsqrtf((float)v + 1.0f);
            gcur[n0 + tid] = 0;
        }
        __syncthreads();
    }
    if (blockIdx.x == 0 && threadIdx.x == 0) off[n] = ebase[nbk];
}

// ---------------- pass 2: per-bucket LDS counting sort -> coalesced csrc/cw write ----------------
// Edge record split into csrc (int, 4B) + cw (bf16 weight, 2B): gather's
// sequential edge stream shrinks 12.8 -> 9.6 MB.

__global__ __launch_bounds__(256) void fill_sort(
    const uint2* __restrict__ ebuf, const int* __restrict__ off,
    const float* __restrict__ dinv, int* __restrict__ gcur,
    int* __restrict__ csrc, bf16* __restrict__ cw, int n, int nbk)
{
    __shared__ int  lcur[256];
    __shared__ uint2 lrec[CAP];   // 36 KB

    for (int b = blockIdx.x; b < nbk; b += gridDim.x) {
        const int n0 = b << BSH2;
        const int n1 = min(n0 + 256, n);
        const int e0 = off[n0], e1 = off[n1];
        const int cnt = e1 - e0;
        if (threadIdx.x < (unsigned)(n1 - n0))
            lcur[threadIdx.x] = off[n0 + threadIdx.x] - e0;
        __syncthreads();
        if (cnt <= CAP) {
            for (int i = threadIdx.x; i < cnt; i += 256) {
                uint2 q = ebuf[e0 + i];
                int s = (int)q.x, d = (int)q.y;
                int p = atomicAdd(&lcur[d - n0], 1);
                lrec[p] = make_uint2(q.x, (unsigned)__float_as_uint(dinv[s] * dinv[d]));
            }
            __syncthreads();
            for (int i = threadIdx.x; i < cnt; i += 256) {
                uint2 r = lrec[i];
                csrc[e0 + i] = (int)r.x;
                cw[e0 + i]   = (bf16)__uint_as_float(r.y);
            }
        } else {
            for (int i = threadIdx.x; i < cnt; i += 256) {
                uint2 q = ebuf[e0 + i];
                int s = (int)q.x, d = (int)q.y;
                int p = off[d] + atomicAdd(&gcur[d], 1);
                csrc[p] = s;
                cw[p]   = (bf16)(dinv[s] * dinv[d]);
            }
        }
        __syncthreads();
    }
}

// ---------------- MFMA GEMM (swapped operands), bf16 activation input ----------------
// 2-term: C^T = (Whi + Wlo)^T @ Ah^T. Output targets optional:
// ohi (bf16, lin1->lin2), oq (fp8 mirror, conv hidden state).

__global__ __launch_bounds__(256) void gemm_mfma(
    const bf16* __restrict__ ahi,
    const float* __restrict__ W, const float* __restrict__ bias,
    bf16* __restrict__ ohi, unsigned char* __restrict__ oq,
    int n_rows, int relu_out)
{
    const int lane = threadIdx.x & 63;
    const int wv   = threadIdx.x >> 6;
    const int col0 = wv * 32;
    const int l15  = lane & 15;
    const int lg   = lane >> 4;

    bf16x8 whi[2][4], wlo[2][4];
    #pragma unroll
    for (int t = 0; t < 2; t++) {
        int c = col0 + 16 * t + l15;
        #pragma unroll
        for (int ks = 0; ks < 4; ks++) {
            #pragma unroll
            for (int j = 0; j < 8; j++) {
                float wvv = W[(ks * 32 + lg * 8 + j) * 128 + c];
                bf16 h = (bf16)wvv;
                whi[t][ks][j] = h;
                wlo[t][ks][j] = (bf16)(wvv - (float)h);
            }
        }
    }

    const int nrt = n_rows >> 4;
    for (int rt = blockIdx.x; rt < nrt; rt += gridDim.x) {
        const int row = rt * 16 + l15;
        const bf16* pah = ahi + (size_t)row * 128 + lg * 8;
        bf16x8 Ah[4];
        #pragma unroll
        for (int ks = 0; ks < 4; ks++)
            Ah[ks] = *(const bf16x8*)(pah + ks * 32);
        #pragma unroll
        for (int t = 0; t < 2; t++) {
            f32x4 acc = {0.f, 0.f, 0.f, 0.f};
            #pragma unroll
            for (int ks = 0; ks < 4; ks++) {
                acc = __builtin_amdgcn_mfma_f32_16x16x32_bf16(wlo[t][ks], Ah[ks], acc, 0, 0, 0);
                acc = __builtin_amdgcn_mfma_f32_16x16x32_bf16(whi[t][ks], Ah[ks], acc, 0, 0, 0);
            }
            const int c0 = col0 + 16 * t + lg * 4;
            f32x4 bv = {0.f, 0.f, 0.f, 0.f};
            if (bias) bv = *(const f32x4*)(bias + c0);
            float v0 = acc[0] + bv[0], v1 = acc[1] + bv[1];
            float v2 = acc[2] + bv[2], v3 = acc[3] + bv[3];
            if (relu_out) {
                v0 = fmaxf(v0, 0.f); v1 = fmaxf(v1, 0.f);
                v2 = fmaxf(v2, 0.f); v3 = fmaxf(v3, 0.f);
            }
            size_t base = (size_t)(rt * 16 + l15) * 128 + c0;
            if (ohi) {
                bf16x4 h;
                h[0] = (bf16)v0; h[1] = (bf16)v1; h[2] = (bf16)v2; h[3] = (bf16)v3;
                *(bf16x4*)(ohi + base) = h;
            }
            if (oq) {
                int p = __builtin_amdgcn_cvt_pk_fp8_f32(v0, v1, 0, false);
                p = __builtin_amdgcn_cvt_pk_fp8_f32(v2, v3, p, true);
                *(unsigned int*)(oq + base) = (unsigned int)p;
            }
        }
    }
}

// ---------------- MFMA GEMM, fp32 input (layer 1): split x in-register -> fp8 only ----------------

__global__ __launch_bounds__(256) void gemm_mfma_x(
    const float* __restrict__ X, const float* __restrict__ W,
    unsigned char* __restrict__ oq, int n_rows)
{
    const int lane = threadIdx.x & 63;
    const int wv   = threadIdx.x >> 6;
    const int col0 = wv * 32;
    const int l15  = lane & 15;
    const int lg   = lane >> 4;

    bf16x8 whi[2][4], wlo[2][4];
    #pragma unroll
    for (int t = 0; t < 2; t++) {
        int c = col0 + 16 * t + l15;
        #pragma unroll
        for (int ks = 0; ks < 4; ks++) {
            #pragma unroll
            for (int j = 0; j < 8; j++) {
                float wvv = W[(ks * 32 + lg * 8 + j) * 128 + c];
                bf16 h = (bf16)wvv;
                whi[t][ks][j] = h;
                wlo[t][ks][j] = (bf16)(wvv - (float)h);
            }
        }
    }

    const int nrt = n_rows >> 4;
    for (int rt = blockIdx.x; rt < nrt; rt += gridDim.x) {
        const int row = rt * 16 + l15;
        const float* px = X + (size_t)row * 128 + lg * 8;
        bf16x8 Ah[4], Al[4];
        #pragma unroll
        for (int ks = 0; ks < 4; ks++) {
            float4 v0 = *(const float4*)(px + ks * 32);
            float4 v1 = *(const float4*)(px + ks * 32 + 4);
            float vv[8] = {v0.x, v0.y, v0.z, v0.w, v1.x, v1.y, v1.z, v1.w};
            #pragma unroll
            for (int j = 0; j < 8; j++) {
                bf16 h = (bf16)vv[j];
                Ah[ks][j] = h;
                Al[ks][j] = (bf16)(vv[j] - (float)h);
            }
        }
        #pragma unroll
        for (int t = 0; t < 2; t++) {
            f32x4 acc = {0.f, 0.f, 0.f, 0.f};
            #pragma unroll
            for (int ks = 0; ks < 4; ks++) {
                acc = __builtin_amdgcn_mfma_f32_16x16x32_bf16(whi[t][ks], Al[ks], acc, 0, 0, 0);
                acc = __builtin_amdgcn_mfma_f32_16x16x32_bf16(wlo[t][ks], Ah[ks], acc, 0, 0, 0);
                acc = __builtin_amdgcn_mfma_f32_16x16x32_bf16(whi[t][ks], Ah[ks], acc, 0, 0, 0);
            }
            const int c0 = col0 + 16 * t + lg * 4;
            size_t base = (size_t)(rt * 16 + l15) * 128 + c0;
            int p = __builtin_amdgcn_cvt_pk_fp8_f32(acc[0], acc[1], 0, false);
            p = __builtin_amdgcn_cvt_pk_fp8_f32(acc[2], acc[3], p, true);
            *(unsigned int*)(oq + base) = (unsigned int)p;
        }
    }
}

// ---------------- CSR gather aggregation: fp8 hidden state, split csrc/cw edge stream ----------------

__global__ __launch_bounds__(256) void gather_agg_split(
    const unsigned char* __restrict__ hq,
    const int* __restrict__ csrc, const bf16* __restrict__ cw,
    const int* __restrict__ off,
    const float* __restrict__ dinv, const float* __restrict__ bias,
    bf16* __restrict__ ohi, int n)
{
    int lane = threadIdx.x & 63;
    int wid  = (blockIdx.x * 256 + threadIdx.x) >> 6;
    int nw   = (gridDim.x * 256) >> 6;

    const int f = 2 * lane;
    float bb0 = bias[f], bb1 = bias[f + 1];

    for (int node = wid; node < n; node += nw) {
        float sn = dinv[node]; sn *= sn;
        size_t nb = (size_t)node * 128 + f;
        unsigned short sq = *(const unsigned short*)(hq + nb);
        f32x2 sv = __builtin_amdgcn_cvt_pk_f32_fp8((int)(unsigned)sq, false);
        float a0 = fmaf(sv[0], sn, bb0);
        float a1 = fmaf(sv[1], sn, bb1);

        int e0 = off[node], e1 = off[node + 1];
        int e = e0;
        for (; e + 8 <= e1; e += 8) {
            int s[8];
            bf16 wv[8];
            #pragma unroll
            for (int j = 0; j < 8; j++) s[j] = csrc[e + j];
            #pragma unroll
            for (int j = 0; j < 8; j++) wv[j] = cw[e + j];
            unsigned short rw[8];
            #pragma unroll
            for (int j = 0; j < 8; j++)
                rw[j] = *(const unsigned short*)(hq + (size_t)s[j] * 128 + f);
            #pragma unroll
            for (int j = 0; j < 8; j++) {
                float w = (float)wv[j];
                f32x2 mv = __builtin_amdgcn_cvt_pk_f32_fp8((int)(unsigned)rw[j], false);
                a0 = fmaf(mv[0], w, a0);
                a1 = fmaf(mv[1], w, a1);
            }
        }
        for (; e + 4 <= e1; e += 4) {
            int s[4];
            bf16 wv[4];
            #pragma unroll
            for (int j = 0; j < 4; j++) s[j] = csrc[e + j];
            #pragma unroll
            for (int j = 0; j < 4; j++) wv[j] = cw[e + j];
            unsigned short rw[4];
            #pragma unroll
            for (int j = 0; j < 4; j++)
                rw[j] = *(const unsigned short*)(hq + (size_t)s[j] * 128 + f);
            #pragma unroll
            for (int j = 0; j < 4; j++) {
                float w = (float)wv[j];
                f32x2 mv = __builtin_amdgcn_cvt_pk_f32_fp8((int)(unsigned)rw[j], false);
                a0 = fmaf(mv[0], w, a0);
                a1 = fmaf(mv[1], w, a1);
            }
        }
        for (; e < e1; e++) {
            int s = csrc[e];
            float w = (float)cw[e];
            unsigned short rwv = *(const unsigned short*)(hq + (size_t)s * 128 + f);
            f32x2 mv = __builtin_amdgcn_cvt_pk_f32_fp8((int)(unsigned)rwv, false);
            a0 = fmaf(mv[0], w, a0);
            a1 = fmaf(mv[1], w, a1);
        }

        a0 = fmaxf(a0, 0.f);
        a1 = fmaxf(a1, 0.f);
        bf16x2 oh;
        oh[0] = (bf16)a0;
        oh[1] = (bf16)a1;
        *(bf16x2*)(ohi + nb) = oh;
    }
}

// ---------------- lin2 + log_softmax via MFMA (swapped operands), bf16-hi input ----------------

__global__ __launch_bounds__(256) void lin2_mfma_lsm(
    const bf16* __restrict__ hhi,
    const float* __restrict__ W, const float* __restrict__ bias,
    float* __restrict__ out, int n)
{
    const int lane = threadIdx.x & 63;
    const int l15  = lane & 15;
    const int lg   = lane >> 4;

    bf16x8 whi[3][4], wlo[3][4];
    #pragma unroll
    for (int t = 0; t < 3; t++) {
        int c = t * 16 + l15;
        bool valid = c < 40;
        #pragma unroll
        for (int ks = 0; ks < 4; ks++) {
            #pragma unroll
            for (int j = 0; j < 8; j++) {
                float wv = valid ? W[(ks * 32 + lg * 8 + j) * 40 + c] : 0.f;
                bf16 h = (bf16)wv;
                whi[t][ks][j] = h;
                wlo[t][ks][j] = (bf16)(wv - (float)h);
            }
        }
    }
    f32x4 bb[3];
    bool vstore[3];
    #pragma unroll
    for (int t = 0; t < 3; t++) {
        int c0 = t * 16 + lg * 4;
        vstore[t] = (c0 < 40);
        if (vstore[t]) bb[t] = *(const f32x4*)(bias + c0);
        else bb[t] = (f32x4){0.f, 0.f, 0.f, 0.f};
    }

    int wtile = (blockIdx.x * 256 + threadIdx.x) >> 6;
    int nwt   = (gridDim.x * 256) >> 6;
    int ntiles = (n + 15) >> 4;

    for (int rt = wtile; rt < ntiles; rt += nwt) {
        int arow = rt * 16 + l15;
        if (arow >= n) arow = n - 1;
        const bf16* pah = hhi + (size_t)arow * 128 + lg * 8;
        bf16x8 Ah[4];
        #pragma unroll
        for (int ks = 0; ks < 4; ks++)
            Ah[ks] = *(const bf16x8*)(pah + ks * 32);
        f32x4 acc[3];
        #pragma unroll
        for (int t = 0; t < 3; t++) {
            acc[t] = (f32x4){0.f, 0.f, 0.f, 0.f};
            #pragma unroll
            for (int ks = 0; ks < 4; ks++) {
                acc[t] = __builtin_amdgcn_mfma_f32_16x16x32_bf16(wlo[t][ks], Ah[ks], acc[t], 0, 0, 0);
                acc[t] = __builtin_amdgcn_mfma_f32_16x16x32_bf16(whi[t][ks], Ah[ks], acc[t], 0, 0, 0);
            }
        }
        float m = -INFINITY;
        #pragma unroll
        for (int t = 0; t < 3; t++) {
            if (vstore[t]) {
                #pragma unroll
                for (int r = 0; r < 4; r++) m = fmaxf(m, acc[t][r] + bb[t][r]);
            }
        }
        m = fmaxf(m, __shfl_xor(m, 16, 64));
        m = fmaxf(m, __shfl_xor(m, 32, 64));
        float s = 0.f;
        #pragma unroll
        for (int t = 0; t < 3; t++) {
            if (vstore[t]) {
                #pragma unroll
                for (int r = 0; r < 4; r++) s += __expf(acc[t][r] + bb[t][r] - m);
            }
        }
        s += __shfl_xor(s, 16, 64);
        s += __shfl_xor(s, 32, 64);
        float ls = __logf(s) + m;

        int node = rt * 16 + l15;
        if (node < n) {
            #pragma unroll
            for (int t = 0; t < 3; t++) {
                if (vstore[t]) {
                    f32x4 o;
                    #pragma unroll
                    for (int r = 0; r < 4; r++) o[r] = acc[t][r] + bb[t][r] - ls;
                    *(f32x4*)(out + (size_t)node * 40 + t * 16 + lg * 4) = o;
                }
            }
        }
    }
}

// ---------------- launch ----------------

static inline size_t align256(size_t x) { return (x + 255) & ~(size_t)255; }

extern "C" void kernel_launch(void* const* d_in, const int* in_sizes, int n_in,
                              void* d_out, int out_size, void* d_ws, size_t ws_size,
                              hipStream_t stream)
{
    const float* x   = (const float*)d_in[0];
    const int*   ei  = (const int*)d_in[1];
    const float* W1  = (const float*)d_in[2];  const float* b1  = (const float*)d_in[3];
    const float* W2  = (const float*)d_in[4];  const float* b2  = (const float*)d_in[5];
    const float* W3  = (const float*)d_in[6];  const float* b3  = (const float*)d_in[7];
    const float* l1w = (const float*)d_in[8];  const float* l1b = (const float*)d_in[9];
    const float* l2w = (const float*)d_in[10]; const float* l2b = (const float*)d_in[11];

    const int N = in_sizes[0] / 128;
    const int E = in_sizes[1] / 2;
    const int* src = ei;
    const int* dst = ei + E;

    char* wsb = (char*)d_ws;
    size_t o = 0;
    int*   gcur  = (int*)(wsb + o);   o = align256(o + (size_t)N * 4);        // fill_sort fallback cursors
    int*   off   = (int*)(wsb + o);   o = align256(o + (size_t)(N + 1) * 4);
    int*   bhist = (int*)(wsb + o);   o = align256(o + (size_t)512 * 4);
    int*   bcur  = (int*)(wsb + o);   o = align256(o + (size_t)512 * 4);
    int*   ebase = (int*)(wsb + o);   o = align256(o + (size_t)513 * 4);
    int*   csrc  = (int*)(wsb + o);   o = align256(o + (size_t)E * 4);
    bf16*  cw    = (bf16*)(wsb + o);  o = align256(o + (size_t)E * 2);
    float* dinv  = (float*)(wsb + o); o = align256(o + (size_t)N * 4);
    bf16*  ahi   = (bf16*)(wsb + o);  o = align256(o + (size_t)N * 128 * 2);
    bf16*  hhi   = (bf16*)(wsb + o);  o = align256(o + (size_t)N * 128 * 2);
    unsigned char* hq = (unsigned char*)(wsb + o); o = align256(o + (size_t)N * 128);

    uint2* ebuf = (uint2*)hhi;   // dead until lin1; 12.8MB < 25.6MB region

    float* outp = (float*)d_out;
    const int nbk  = (N + 255) >> BSH2;                 // 391 buckets
    const int npart = (E + PCH - 1) / PCH;              // 391 chunks

    // ---- CSR build: bucket hist, scan, partition, per-bucket off/dinv(+gcur=0), counting sort ----
    zero_i32<<<4, 256, 0, stream>>>(bhist, 1024);       // bhist + bcur (contiguous)
    bhist_k<<<1024, 256, 0, stream>>>(dst, bhist, E);
    bscan512<<<1, 64, 0, stream>>>(bhist, ebase);
    partition_edges<<<npart, 256, 0, stream>>>(src, dst, ebase, bcur, ebuf, E, nbk);
    bucket_off_dinv<<<nbk, 256, 0, stream>>>(ebuf, ebase, off, dinv, gcur, N, nbk);
    fill_sort<<<nbk, 256, 0, stream>>>(ebuf, off, dinv, gcur, csrc, cw, N, nbk);

    // ---- layer 1: gemm from fp32 x -> fp8 hidden state ----
    gemm_mfma_x<<<1024, 256, 0, stream>>>(x, W1, hq, N);
    gather_agg_split<<<8192, 256, 0, stream>>>(hq, csrc, cw, off, dinv, b1, ahi, N);

    // ---- layer 2 ----
    gemm_mfma<<<1024, 256, 0, stream>>>(ahi, W2, nullptr, nullptr, hq, N, 0);
    gather_agg_split<<<8192, 256, 0, stream>>>(hq, csrc, cw, off, dinv, b2, ahi, N);

    // ---- layer 3 ----
    gemm_mfma<<<1024, 256, 0, stream>>>(ahi, W3, nullptr, nullptr, hq, N, 0);
    gather_agg_split<<<8192, 256, 0, stream>>>(hq, csrc, cw, off, dinv, b3, ahi, N);

    // ---- lin1 (+bias+relu) -> bf16 hi (lin2 input) ----
    gemm_mfma<<<1024, 256, 0, stream>>>(ahi, l1w, l1b, hhi, nullptr, N, 1);

    // ---- lin2 + log_softmax ----
    lin2_mfma_lsm<<<512, 256, 0, stream>>>(hhi, l2w, l2b, outp, N);
}

// Round 23
// 345.391 us; speedup vs baseline: 1.0191x; 1.0191x over previous
//
#include <hip/hip_runtime.h>
#include <math.h>

typedef __bf16 bf16;
typedef bf16  bf16x8 __attribute__((ext_vector_type(8)));
typedef bf16  bf16x4 __attribute__((ext_vector_type(4)));
typedef bf16  bf16x2 __attribute__((ext_vector_type(2)));
typedef float f32x4  __attribute__((ext_vector_type(4)));
typedef float f32x2  __attribute__((ext_vector_type(2)));

#define BSH2 8        // bucket = 256 nodes
#define PCH  4096     // edges per partition chunk (391 blocks)
#define CAP  4608     // LDS record capacity per bucket (mean 4096, 8 sigma margin)

// ---------------- helpers ----------------

__global__ void zero_i32(int* __restrict__ p, int n) {
    int i = blockIdx.x * blockDim.x + threadIdx.x;
    if (i < n) p[i] = 0;
}

// ---------------- bucket histogram of dst>>8 (sequential read, LDS hist) ----------------

__global__ __launch_bounds__(256) void bhist_k(const int* __restrict__ dst,
                                               int* __restrict__ bhist, int E) {
    __shared__ int lh[512];
    for (int b = threadIdx.x; b < 512; b += 256) lh[b] = 0;
    __syncthreads();
    int i = blockIdx.x * 256 + threadIdx.x;
    int stride = gridDim.x * 256;
    for (; i < E; i += stride) atomicAdd(&lh[dst[i] >> BSH2], 1);
    __syncthreads();
    for (int b = threadIdx.x; b < 512; b += 256)
        if (lh[b]) atomicAdd(&bhist[b], lh[b]);
}

// single wave: exclusive scan bhist[512] -> ebase[513]
__global__ __launch_bounds__(64) void bscan512(const int* __restrict__ bhist,
                                               int* __restrict__ ebase) {
    int lane = threadIdx.x;
    __shared__ int carry_s;
    if (lane == 0) carry_s = 0;
    __syncthreads();
    for (int base = 0; base < 512; base += 64) {
        int v = bhist[base + lane];
        int x = v;
        #pragma unroll
        for (int o = 1; o < 64; o <<= 1) {
            int t = __shfl_up(x, o, 64);
            if (lane >= o) x += t;
        }
        int carry = carry_s;
        ebase[base + lane] = carry + x - v;
        int total = __shfl(x, 63, 64);
        __syncthreads();
        if (lane == 0) carry_s = carry + total;
        __syncthreads();
    }
    if (lane == 0) ebase[512] = carry_s;
}

// ---------------- pass 1: partition edges by dst bucket, coalesced runs ----------------

__global__ __launch_bounds__(256) void partition_edges(
    const int* __restrict__ src, const int* __restrict__ dst,
    const int* __restrict__ ebase, int* __restrict__ bcur,
    uint2* __restrict__ ebuf, int E, int nbk)
{
    __shared__ int lhist[512];
    __shared__ int lbase[512];
    __shared__ int lcur[512];
    __shared__ int gbase[512];
    __shared__ int csum[8];
    __shared__ unsigned short stage[PCH];

    const int tid = threadIdx.x, lane = tid & 63, wv = tid >> 6;

    for (int base = blockIdx.x * PCH; base < E; base += gridDim.x * PCH) {
        const int cnt = min(PCH, E - base);

        for (int b = tid; b < 512; b += 256) lhist[b] = 0;
        __syncthreads();
        for (int i = tid; i < cnt; i += 256)
            atomicAdd(&lhist[dst[base + i] >> BSH2], 1);
        __syncthreads();
        for (int c = wv; c < 8; c += 4) {
            int idx = c * 64 + lane;
            int v = lhist[idx], x = v;
            #pragma unroll
            for (int o = 1; o < 64; o <<= 1) {
                int t = __shfl_up(x, o, 64);
                if (lane >= o) x += t;
            }
            lbase[idx] = x - v;
            if (lane == 63) csum[c] = x;
        }
        __syncthreads();
        if (tid == 0) {
            int acc = 0;
            #pragma unroll
            for (int c = 0; c < 8; c++) { int t = csum[c]; csum[c] = acc; acc += t; }
        }
        __syncthreads();
        for (int c = wv; c < 8; c += 4) {
            int idx = c * 64 + lane;
            lbase[idx] += csum[c];
            lcur[idx] = lbase[idx];
        }
        __syncthreads();
        for (int i = tid; i < cnt; i += 256) {
            int b = dst[base + i] >> BSH2;
            int p = atomicAdd(&lcur[b], 1);
            stage[p] = (unsigned short)i;
        }
        __syncthreads();
        for (int b = tid; b < nbk; b += 256) {
            int cb = lcur[b] - lbase[b];
            if (cb > 0) gbase[b] = ebase[b] + atomicAdd(&bcur[b], cb);
        }
        __syncthreads();
        for (int k = tid; k < cnt; k += 256) {
            int i = base + (int)stage[k];
            int s = src[i], d = dst[i];
            int b = d >> BSH2;
            ebuf[gbase[b] + (k - lbase[b])] = make_uint2((unsigned)s, (unsigned)d);
        }
        __syncthreads();
    }
}

// ---------------- pass 1.5: per-bucket deg count -> off[] and dinv[]; zeroes gcur ----------------

__global__ __launch_bounds__(256) void bucket_off_dinv(
    const uint2* __restrict__ ebuf, const int* __restrict__ ebase,
    int* __restrict__ off, float* __restrict__ dinv, int* __restrict__ gcur,
    int n, int nbk)
{
    __shared__ int ldeg[256];
    __shared__ int wsum[4];
    const int tid = threadIdx.x, lane = tid & 63, wv = tid >> 6;

    for (int b = blockIdx.x; b < nbk; b += gridDim.x) {
        const int n0 = b << BSH2;
        const int n1 = min(n0 + 256, n);
        const int e0 = ebase[b], e1 = ebase[b + 1];

        ldeg[tid] = 0;
        __syncthreads();
        for (int i = e0 + tid; i < e1; i += 256)
            atomicAdd(&ldeg[(int)ebuf[i].y - n0], 1);
        __syncthreads();

        int v = ldeg[tid];
        int x = v;
        #pragma unroll
        for (int o = 1; o < 64; o <<= 1) {
            int t = __shfl_up(x, o, 64);
            if (lane >= o) x += t;
        }
        if (lane == 63) wsum[wv] = x;
        __syncthreads();
        int wbase = 0;
        #pragma unroll
        for (int w = 0; w < 4; w++) if (w < wv) wbase += wsum[w];
        int pref = wbase + x - v;   // exclusive prefix

        if (n0 + tid < n1) {
            off[n0 + tid]  = e0 + pref;
            dinv[n0 + tid] = rsqrtf((float)v + 1.0f);
            gcur[n0 + tid] = 0;
        }
        __syncthreads();
    }
    if (blockIdx.x == 0 && threadIdx.x == 0) off[n] = ebase[nbk];
}

// ---------------- pass 2: per-bucket LDS counting sort -> coalesced erec write ----------------

__global__ __launch_bounds__(256) void fill_sort(
    const uint2* __restrict__ ebuf, const int* __restrict__ off,
    const float* __restrict__ dinv, int* __restrict__ gcur,
    uint2* __restrict__ erec, int n, int nbk)
{
    __shared__ int  lcur[256];
    __shared__ uint2 lrec[CAP];   // 36 KB

    for (int b = blockIdx.x; b < nbk; b += gridDim.x) {
        const int n0 = b << BSH2;
        const int n1 = min(n0 + 256, n);
        const int e0 = off[n0], e1 = off[n1];
        const int cnt = e1 - e0;
        if (threadIdx.x < (unsigned)(n1 - n0))
            lcur[threadIdx.x] = off[n0 + threadIdx.x] - e0;
        __syncthreads();
        if (cnt <= CAP) {
            for (int i = threadIdx.x; i < cnt; i += 256) {
                uint2 q = ebuf[e0 + i];
                int s = (int)q.x, d = (int)q.y;
                int p = atomicAdd(&lcur[d - n0], 1);
                lrec[p] = make_uint2(q.x, (unsigned)__float_as_uint(dinv[s] * dinv[d]));
            }
            __syncthreads();
            for (int i = threadIdx.x; i < cnt; i += 256)
                erec[e0 + i] = lrec[i];
        } else {
            for (int i = threadIdx.x; i < cnt; i += 256) {
                uint2 q = ebuf[e0 + i];
                int s = (int)q.x, d = (int)q.y;
                int p = off[d] + atomicAdd(&gcur[d], 1);
                erec[p] = make_uint2(q.x, (unsigned)__float_as_uint(dinv[s] * dinv[d]));
            }
        }
        __syncthreads();
    }
}

// ---------------- MFMA GEMM (swapped operands), bf16 activation input ----------------
// 2-term: C^T = (Whi + Wlo)^T @ Ah^T. Output targets optional:
// ohi (bf16, lin1->lin2), oq (fp8 mirror, conv hidden state).

__global__ __launch_bounds__(256) void gemm_mfma(
    const bf16* __restrict__ ahi,
    const float* __restrict__ W, const float* __restrict__ bias,
    bf16* __restrict__ ohi, unsigned char* __restrict__ oq,
    int n_rows, int relu_out)
{
    const int lane = threadIdx.x & 63;
    const int wv   = threadIdx.x >> 6;
    const int col0 = wv * 32;
    const int l15  = lane & 15;
    const int lg   = lane >> 4;

    bf16x8 whi[2][4], wlo[2][4];
    #pragma unroll
    for (int t = 0; t < 2; t++) {
        int c = col0 + 16 * t + l15;
        #pragma unroll
        for (int ks = 0; ks < 4; ks++) {
            #pragma unroll
            for (int j = 0; j < 8; j++) {
                float wvv = W[(ks * 32 + lg * 8 + j) * 128 + c];
                bf16 h = (bf16)wvv;
                whi[t][ks][j] = h;
                wlo[t][ks][j] = (bf16)(wvv - (float)h);
            }
        }
    }

    const int nrt = n_rows >> 4;
    for (int rt = blockIdx.x; rt < nrt; rt += gridDim.x) {
        const int row = rt * 16 + l15;
        const bf16* pah = ahi + (size_t)row * 128 + lg * 8;
        bf16x8 Ah[4];
        #pragma unroll
        for (int ks = 0; ks < 4; ks++)
            Ah[ks] = *(const bf16x8*)(pah + ks * 32);
        #pragma unroll
        for (int t = 0; t < 2; t++) {
            f32x4 acc = {0.f, 0.f, 0.f, 0.f};
            #pragma unroll
            for (int ks = 0; ks < 4; ks++) {
                acc = __builtin_amdgcn_mfma_f32_16x16x32_bf16(wlo[t][ks], Ah[ks], acc, 0, 0, 0);
                acc = __builtin_amdgcn_mfma_f32_16x16x32_bf16(whi[t][ks], Ah[ks], acc, 0, 0, 0);
            }
            const int c0 = col0 + 16 * t + lg * 4;
            f32x4 bv = {0.f, 0.f, 0.f, 0.f};
            if (bias) bv = *(const f32x4*)(bias + c0);
            float v0 = acc[0] + bv[0], v1 = acc[1] + bv[1];
            float v2 = acc[2] + bv[2], v3 = acc[3] + bv[3];
            if (relu_out) {
                v0 = fmaxf(v0, 0.f); v1 = fmaxf(v1, 0.f);
                v2 = fmaxf(v2, 0.f); v3 = fmaxf(v3, 0.f);
            }
            size_t base = (size_t)(rt * 16 + l15) * 128 + c0;
            if (ohi) {
                bf16x4 h;
                h[0] = (bf16)v0; h[1] = (bf16)v1; h[2] = (bf16)v2; h[3] = (bf16)v3;
                *(bf16x4*)(ohi + base) = h;
            }
            if (oq) {
                int p = __builtin_amdgcn_cvt_pk_fp8_f32(v0, v1, 0, false);
                p = __builtin_amdgcn_cvt_pk_fp8_f32(v2, v3, p, true);
                *(unsigned int*)(oq + base) = (unsigned int)p;
            }
        }
    }
}

// ---------------- MFMA GEMM, fp32 input (layer 1): split x in-register -> fp8 only ----------------

__global__ __launch_bounds__(256) void gemm_mfma_x(
    const float* __restrict__ X, const float* __restrict__ W,
    unsigned char* __restrict__ oq, int n_rows)
{
    const int lane = threadIdx.x & 63;
    const int wv   = threadIdx.x >> 6;
    const int col0 = wv * 32;
    const int l15  = lane & 15;
    const int lg   = lane >> 4;

    bf16x8 whi[2][4], wlo[2][4];
    #pragma unroll
    for (int t = 0; t < 2; t++) {
        int c = col0 + 16 * t + l15;
        #pragma unroll
        for (int ks = 0; ks < 4; ks++) {
            #pragma unroll
            for (int j = 0; j < 8; j++) {
                float wvv = W[(ks * 32 + lg * 8 + j) * 128 + c];
                bf16 h = (bf16)wvv;
                whi[t][ks][j] = h;
                wlo[t][ks][j] = (bf16)(wvv - (float)h);
            }
        }
    }

    const int nrt = n_rows >> 4;
    for (int rt = blockIdx.x; rt < nrt; rt += gridDim.x) {
        const int row = rt * 16 + l15;
        const float* px = X + (size_t)row * 128 + lg * 8;
        bf16x8 Ah[4], Al[4];
        #pragma unroll
        for (int ks = 0; ks < 4; ks++) {
            float4 v0 = *(const float4*)(px + ks * 32);
            float4 v1 = *(const float4*)(px + ks * 32 + 4);
            float vv[8] = {v0.x, v0.y, v0.z, v0.w, v1.x, v1.y, v1.z, v1.w};
            #pragma unroll
            for (int j = 0; j < 8; j++) {
                bf16 h = (bf16)vv[j];
                Ah[ks][j] = h;
                Al[ks][j] = (bf16)(vv[j] - (float)h);
            }
        }
        #pragma unroll
        for (int t = 0; t < 2; t++) {
            f32x4 acc = {0.f, 0.f, 0.f, 0.f};
            #pragma unroll
            for (int ks = 0; ks < 4; ks++) {
                acc = __builtin_amdgcn_mfma_f32_16x16x32_bf16(whi[t][ks], Al[ks], acc, 0, 0, 0);
                acc = __builtin_amdgcn_mfma_f32_16x16x32_bf16(wlo[t][ks], Ah[ks], acc, 0, 0, 0);
                acc = __builtin_amdgcn_mfma_f32_16x16x32_bf16(whi[t][ks], Ah[ks], acc, 0, 0, 0);
            }
            const int c0 = col0 + 16 * t + lg * 4;
            size_t base = (size_t)(rt * 16 + l15) * 128 + c0;
            int p = __builtin_amdgcn_cvt_pk_fp8_f32(acc[0], acc[1], 0, false);
            p = __builtin_amdgcn_cvt_pk_fp8_f32(acc[2], acc[3], p, true);
            *(unsigned int*)(oq + base) = (unsigned int)p;
        }
    }
}

// ---------------- CSR gather aggregation: fp8 hidden state (self + messages), bf16 out ----------------

__global__ __launch_bounds__(256) void gather_agg_split(
    const unsigned char* __restrict__ hq,
    const uint2* __restrict__ erec, const int* __restrict__ off,
    const float* __restrict__ dinv, const float* __restrict__ bias,
    bf16* __restrict__ ohi, int n)
{
    int lane = threadIdx.x & 63;
    int wid  = (blockIdx.x * 256 + threadIdx.x) >> 6;
    int nw   = (gridDim.x * 256) >> 6;

    const int f = 2 * lane;
    float bb0 = bias[f], bb1 = bias[f + 1];

    for (int node = wid; node < n; node += nw) {
        float sn = dinv[node]; sn *= sn;
        size_t nb = (size_t)node * 128 + f;
        unsigned short sq = *(const unsigned short*)(hq + nb);
        f32x2 sv = __builtin_amdgcn_cvt_pk_f32_fp8((int)(unsigned)sq, false);
        float a0 = fmaf(sv[0], sn, bb0);
        float a1 = fmaf(sv[1], sn, bb1);

        int e0 = off[node], e1 = off[node + 1];
        int e = e0;
        for (; e + 8 <= e1; e += 8) {
            uint2 q[8];
            #pragma unroll
            for (int j = 0; j < 8; j++) q[j] = erec[e + j];
            unsigned short rw[8];
            #pragma unroll
            for (int j = 0; j < 8; j++)
                rw[j] = *(const unsigned short*)(hq + (size_t)q[j].x * 128 + f);
            #pragma unroll
            for (int j = 0; j < 8; j++) {
                float w = __uint_as_float(q[j].y);
                f32x2 mv = __builtin_amdgcn_cvt_pk_f32_fp8((int)(unsigned)rw[j], false);
                a0 = fmaf(mv[0], w, a0);
                a1 = fmaf(mv[1], w, a1);
            }
        }
        for (; e + 4 <= e1; e += 4) {
            uint2 q[4];
            #pragma unroll
            for (int j = 0; j < 4; j++) q[j] = erec[e + j];
            unsigned short rw[4];
            #pragma unroll
            for (int j = 0; j < 4; j++)
                rw[j] = *(const unsigned short*)(hq + (size_t)q[j].x * 128 + f);
            #pragma unroll
            for (int j = 0; j < 4; j++) {
                float w = __uint_as_float(q[j].y);
                f32x2 mv = __builtin_amdgcn_cvt_pk_f32_fp8((int)(unsigned)rw[j], false);
                a0 = fmaf(mv[0], w, a0);
                a1 = fmaf(mv[1], w, a1);
            }
        }
        for (; e < e1; e++) {
            uint2 q = erec[e];
            float w = __uint_as_float(q.y);
            unsigned short rwv = *(const unsigned short*)(hq + (size_t)q.x * 128 + f);
            f32x2 mv = __builtin_amdgcn_cvt_pk_f32_fp8((int)(unsigned)rwv, false);
            a0 = fmaf(mv[0], w, a0);
            a1 = fmaf(mv[1], w, a1);
        }

        a0 = fmaxf(a0, 0.f);
        a1 = fmaxf(a1, 0.f);
        bf16x2 oh;
        oh[0] = (bf16)a0;
        oh[1] = (bf16)a1;
        *(bf16x2*)(ohi + nb) = oh;
    }
}

// ---------------- lin2 + log_softmax via MFMA (swapped operands), bf16-hi input ----------------

__global__ __launch_bounds__(256) void lin2_mfma_lsm(
    const bf16* __restrict__ hhi,
    const float* __restrict__ W, const float* __restrict__ bias,
    float* __restrict__ out, int n)
{
    const int lane = threadIdx.x & 63;
    const int l15  = lane & 15;
    const int lg   = lane >> 4;

    bf16x8 whi[3][4], wlo[3][4];
    #pragma unroll
    for (int t = 0; t < 3; t++) {
        int c = t * 16 + l15;
        bool valid = c < 40;
        #pragma unroll
        for (int ks = 0; ks < 4; ks++) {
            #pragma unroll
            for (int j = 0; j < 8; j++) {
                float wv = valid ? W[(ks * 32 + lg * 8 + j) * 40 + c] : 0.f;
                bf16 h = (bf16)wv;
                whi[t][ks][j] = h;
                wlo[t][ks][j] = (bf16)(wv - (float)h);
            }
        }
    }
    f32x4 bb[3];
    bool vstore[3];
    #pragma unroll
    for (int t = 0; t < 3; t++) {
        int c0 = t * 16 + lg * 4;
        vstore[t] = (c0 < 40);
        if (vstore[t]) bb[t] = *(const f32x4*)(bias + c0);
        else bb[t] = (f32x4){0.f, 0.f, 0.f, 0.f};
    }

    int wtile = (blockIdx.x * 256 + threadIdx.x) >> 6;
    int nwt   = (gridDim.x * 256) >> 6;
    int ntiles = (n + 15) >> 4;

    for (int rt = wtile; rt < ntiles; rt += nwt) {
        int arow = rt * 16 + l15;
        if (arow >= n) arow = n - 1;
        const bf16* pah = hhi + (size_t)arow * 128 + lg * 8;
        bf16x8 Ah[4];
        #pragma unroll
        for (int ks = 0; ks < 4; ks++)
            Ah[ks] = *(const bf16x8*)(pah + ks * 32);
        f32x4 acc[3];
        #pragma unroll
        for (int t = 0; t < 3; t++) {
            acc[t] = (f32x4){0.f, 0.f, 0.f, 0.f};
            #pragma unroll
            for (int ks = 0; ks < 4; ks++) {
                acc[t] = __builtin_amdgcn_mfma_f32_16x16x32_bf16(wlo[t][ks], Ah[ks], acc[t], 0, 0, 0);
                acc[t] = __builtin_amdgcn_mfma_f32_16x16x32_bf16(whi[t][ks], Ah[ks], acc[t], 0, 0, 0);
            }
        }
        float m = -INFINITY;
        #pragma unroll
        for (int t = 0; t < 3; t++) {
            if (vstore[t]) {
                #pragma unroll
                for (int r = 0; r < 4; r++) m = fmaxf(m, acc[t][r] + bb[t][r]);
            }
        }
        m = fmaxf(m, __shfl_xor(m, 16, 64));
        m = fmaxf(m, __shfl_xor(m, 32, 64));
        float s = 0.f;
        #pragma unroll
        for (int t = 0; t < 3; t++) {
            if (vstore[t]) {
                #pragma unroll
                for (int r = 0; r < 4; r++) s += __expf(acc[t][r] + bb[t][r] - m);
            }
        }
        s += __shfl_xor(s, 16, 64);
        s += __shfl_xor(s, 32, 64);
        float ls = __logf(s) + m;

        int node = rt * 16 + l15;
        if (node < n) {
            #pragma unroll
            for (int t = 0; t < 3; t++) {
                if (vstore[t]) {
                    f32x4 o;
                    #pragma unroll
                    for (int r = 0; r < 4; r++) o[r] = acc[t][r] + bb[t][r] - ls;
                    *(f32x4*)(out + (size_t)node * 40 + t * 16 + lg * 4) = o;
                }
            }
        }
    }
}

// ---------------- launch ----------------

static inline size_t align256(size_t x) { return (x + 255) & ~(size_t)255; }

extern "C" void kernel_launch(void* const* d_in, const int* in_sizes, int n_in,
                              void* d_out, int out_size, void* d_ws, size_t ws_size,
                              hipStream_t stream)
{
    const float* x   = (const float*)d_in[0];
    const int*   ei  = (const int*)d_in[1];
    const float* W1  = (const float*)d_in[2];  const float* b1  = (const float*)d_in[3];
    const float* W2  = (const float*)d_in[4];  const float* b2  = (const float*)d_in[5];
    const float* W3  = (const float*)d_in[6];  const float* b3  = (const float*)d_in[7];
    const float* l1w = (const float*)d_in[8];  const float* l1b = (const float*)d_in[9];
    const float* l2w = (const float*)d_in[10]; const float* l2b = (const float*)d_in[11];

    const int N = in_sizes[0] / 128;
    const int E = in_sizes[1] / 2;
    const int* src = ei;
    const int* dst = ei + E;

    char* wsb = (char*)d_ws;
    size_t o = 0;
    int*   gcur  = (int*)(wsb + o);   o = align256(o + (size_t)N * 4);        // fill_sort fallback cursors
    int*   off   = (int*)(wsb + o);   o = align256(o + (size_t)(N + 1) * 4);
    int*   bhist = (int*)(wsb + o);   o = align256(o + (size_t)512 * 4);
    int*   bcur  = (int*)(wsb + o);   o = align256(o + (size_t)512 * 4);
    int*   ebase = (int*)(wsb + o);   o = align256(o + (size_t)513 * 4);
    uint2* erec  = (uint2*)(wsb + o); o = align256(o + (size_t)E * 8);
    float* dinv  = (float*)(wsb + o); o = align256(o + (size_t)N * 4);
    bf16*  ahi   = (bf16*)(wsb + o);  o = align256(o + (size_t)N * 128 * 2);
    bf16*  hhi   = (bf16*)(wsb + o);  o = align256(o + (size_t)N * 128 * 2);
    unsigned char* hq = (unsigned char*)(wsb + o); o = align256(o + (size_t)N * 128);

    uint2* ebuf = (uint2*)hhi;   // dead until lin1; 12.8MB < 25.6MB region

    float* outp = (float*)d_out;
    const int nbk  = (N + 255) >> BSH2;                 // 391 buckets
    const int npart = (E + PCH - 1) / PCH;              // 391 chunks

    // ---- CSR build: bucket hist, scan, partition, per-bucket off/dinv(+gcur=0), counting sort ----
    zero_i32<<<4, 256, 0, stream>>>(bhist, 1024);       // bhist + bcur (contiguous)
    bhist_k<<<1024, 256, 0, stream>>>(dst, bhist, E);
    bscan512<<<1, 64, 0, stream>>>(bhist, ebase);
    partition_edges<<<npart, 256, 0, stream>>>(src, dst, ebase, bcur, ebuf, E, nbk);
    bucket_off_dinv<<<nbk, 256, 0, stream>>>(ebuf, ebase, off, dinv, gcur, N, nbk);
    fill_sort<<<nbk, 256, 0, stream>>>(ebuf, off, dinv, gcur, erec, N, nbk);

    // ---- layer 1: gemm from fp32 x -> fp8 hidden state ----
    gemm_mfma_x<<<1024, 256, 0, stream>>>(x, W1, hq, N);
    gather_agg_split<<<4096, 256, 0, stream>>>(hq, erec, off, dinv, b1, ahi, N);

    // ---- layer 2 ----
    gemm_mfma<<<1024, 256, 0, stream>>>(ahi, W2, nullptr, nullptr, hq, N, 0);
    gather_agg_split<<<4096, 256, 0, stream>>>(hq, erec, off, dinv, b2, ahi, N);

    // ---- layer 3 ----
    gemm_mfma<<<1024, 256, 0, stream>>>(ahi, W3, nullptr, nullptr, hq, N, 0);
    gather_agg_split<<<4096, 256, 0, stream>>>(hq, erec, off, dinv, b3, ahi, N);

    // ---- lin1 (+bias+relu) -> bf16 hi (lin2 input) ----
    gemm_mfma<<<1024, 256, 0, stream>>>(ahi, l1w, l1b, hhi, nullptr, N, 1);

    // ---- lin2 + log_softmax ----
    lin2_mfma_lsm<<<512, 256, 0, stream>>>(hhi, l2w, l2b, outp, N);
}